// Round 2
// baseline (685.383 us; speedup 1.0000x reference)
//
#include <hip/hip_runtime.h>
#include <math.h>
#include <stdint.h>

#define N_NODES 50000
#define N_EDGES 500000
#define D 128
#define BE 128         // edges per block
#define WROW 72        // Wt global row stride in bf16 (64 real + 8 pad)
#define MROW 136       // LDS row stride in bf16 (128 real + 8 pad, 16B-aligned)
#define LOG2E 1.4426950408889634f
#define LN2   0.6931471805599453f

typedef __attribute__((ext_vector_type(8))) short bf16x8;
typedef __attribute__((ext_vector_type(4))) float floatx4;

__device__ __forceinline__ float fast_sigmoid(float v) {
    return __builtin_amdgcn_rcpf(1.0f + __builtin_amdgcn_exp2f(-v * LOG2E));
}
__device__ __forceinline__ float fast_softplus(float v) {
    float t = __builtin_amdgcn_exp2f(-fabsf(v) * LOG2E);
    return fmaxf(v, 0.0f) + __builtin_amdgcn_logf(1.0f + t) * LN2;
}
__device__ __forceinline__ uint32_t pack_bf16(float a, float b) {
    union { float f; uint32_t u; } ca, cb; ca.f = a; cb.f = b;
    return __builtin_amdgcn_perm(cb.u + 0x8000u, ca.u + 0x8000u, 0x07060302);
}
__device__ __forceinline__ unsigned short f2bf(float f) {
    union { float f; uint32_t u; } c; c.f = f;
    return (unsigned short)((c.u + 0x8000u) >> 16);
}

// Wt padded layout: [kt][n][72 bf16]; block (kt,i) converts k-chunk i for all n.
__global__ __launch_bounds__(256) void wt_prepass(
    const float* __restrict__ Wf, const float* __restrict__ Ws,
    unsigned short* __restrict__ Wt)
{
    const int kt = blockIdx.x >> 3;
    const int i  = blockIdx.x & 7;
    const int n  = threadIdx.x;
    const float* src = (n < 128) ? (Wf + n) : (Ws + (n - 128));
    const int k0 = kt * 64 + i * 8;
    uint32_t u[4];
#pragma unroll
    for (int j = 0; j < 4; j++) {
        float a = src[(size_t)(k0 + 2 * j) * D];
        float b = src[(size_t)(k0 + 2 * j + 1) * D];
        u[j] = pack_bf16(a, b);
    }
    uint4 v; v.x = u[0]; v.y = u[1]; v.z = u[2]; v.w = u[3];
    *(uint4*)(Wt + (size_t)(kt * 256 + n) * WROW + i * 8) = v;
}

// 128 edges x 256 outputs, K=384, bf16 MFMA 16x16x32.
// B (weights) fragments load straight from L2-resident Wt into VGPRs (no LDS).
// A (z) staged in one 34.8KB LDS buffer, one source (x[src]/x[tgt]/edge_attr)
// = 128 K-floats per staging round -> only 2 barriers per 128-K chunk.
// mode1: LDS-repacked coalesced bf16 msg stores + fused degree count.
// mode0: atomicAdd fallback.
__global__ __launch_bounds__(256, 2) void edge_msg_mfma(
    const float* __restrict__ x, const float* __restrict__ edge_attr,
    const int* __restrict__ esrc, const int* __restrict__ etgt,
    const unsigned short* __restrict__ Wt,
    const float* __restrict__ bfp, const float* __restrict__ bsp,
    float* __restrict__ agg, unsigned short* __restrict__ msgs,
    int* __restrict__ cnt, int mode)
{
    __shared__ unsigned short sZ[BE * MROW];   // 34,816 B (reused as msg tile)
    __shared__ int sSrc[BE];
    __shared__ int sTgt[BE];

    const int tid  = threadIdx.x;
    const int lane = tid & 63;
    const int w    = tid >> 6;
    const int e0   = blockIdx.x * BE;

    if (tid < BE) {
        sSrc[tid] = (e0 + tid < N_EDGES) ? esrc[e0 + tid] : 0;
    } else {
        int m = tid - BE;
        sTgt[m] = (e0 + m < N_EDGES) ? etgt[e0 + m] : 0;
    }
    __syncthreads();

    floatx4 acc[8][4];
#pragma unroll
    for (int mt = 0; mt < 8; mt++)
#pragma unroll
        for (int nt = 0; nt < 4; nt++) {
            floatx4 z = {0.f, 0.f, 0.f, 0.f};
            acc[mt][nt] = z;
        }

#pragma unroll 1
    for (int kp = 0; kp < 3; kp++) {
        // ---- stage one full 128-float source row per edge into sZ (bf16) ----
        {
            const int row = tid >> 1;       // 0..127
            const int hf  = tid & 1;        // 64-float half
            const float* src;
            if (kp == 0)      src = x + (size_t)sSrc[row] * D;
            else if (kp == 1) src = x + (size_t)sTgt[row] * D;
            else {
                int eg = e0 + row;
                src = edge_attr + (size_t)(eg < N_EDGES ? eg : 0) * D;
            }
            src += hf * 64;
            uint32_t* dz = (uint32_t*)(sZ + row * MROW + hf * 64);
#pragma unroll
            for (int g = 0; g < 4; g++) {
                float4 a  = *(const float4*)(src + g * 16);
                float4 b  = *(const float4*)(src + g * 16 + 4);
                float4 cc = *(const float4*)(src + g * 16 + 8);
                float4 dd = *(const float4*)(src + g * 16 + 12);
                uint4 u, v;
                u.x = pack_bf16(a.x, a.y);   u.y = pack_bf16(a.z, a.w);
                u.z = pack_bf16(b.x, b.y);   u.w = pack_bf16(b.z, b.w);
                v.x = pack_bf16(cc.x, cc.y); v.y = pack_bf16(cc.z, cc.w);
                v.z = pack_bf16(dd.x, dd.y); v.w = pack_bf16(dd.z, dd.w);
                *(uint4*)(dz + g * 8)     = u;
                *(uint4*)(dz + g * 8 + 4) = v;
            }
        }
        __syncthreads();

        // ---- compute: 2 K-64 tiles against this staged source ----
#pragma unroll
        for (int kh = 0; kh < 2; kh++) {
            const int kt = kp * 2 + kh;
            const unsigned short* wb = Wt + (size_t)kt * 256 * WROW;
#pragma unroll
            for (int ks = 0; ks < 2; ks++) {
                const int kb = ks * 32 + ((lane >> 4) << 3);
                bf16x8 bfr[4];
#pragma unroll
                for (int nt = 0; nt < 4; nt++) {
                    const int n = ((nt < 2) ? (w * 32 + nt * 16)
                                            : (128 + w * 32 + (nt - 2) * 16))
                                  + (lane & 15);
                    bfr[nt] = *(const bf16x8*)(wb + n * WROW + kb);
                }
#pragma unroll
                for (int mt = 0; mt < 8; mt++) {
                    bf16x8 afr = *(const bf16x8*)(sZ + (mt * 16 + (lane & 15)) * MROW
                                                  + kh * 64 + kb);
#pragma unroll
                    for (int nt = 0; nt < 4; nt++)
                        acc[mt][nt] = __builtin_amdgcn_mfma_f32_16x16x32_bf16(
                            afr, bfr[nt], acc[mt][nt], 0, 0, 0);
                }
            }
        }
        __syncthreads();
    }

    // ---- epilogue: bias + gate ----
    if (mode) {
        unsigned short* sM = sZ;   // reuse: 128 x MROW bf16 tile
#pragma unroll
        for (int nt = 0; nt < 2; nt++) {
            const int col = w * 32 + nt * 16 + (lane & 15);
            const float bF = bfp[col];
            const float bS = bsp[col];
#pragma unroll
            for (int mt = 0; mt < 8; mt++) {
#pragma unroll
                for (int r = 0; r < 4; r++) {
                    int mm = mt * 16 + ((lane >> 4) << 2) + r;
                    float f = acc[mt][nt][r] + bF;
                    float s = acc[mt][nt + 2][r] + bS;
                    sM[mm * MROW + col] = f2bf(fast_sigmoid(f) * fast_softplus(s));
                }
            }
        }
        __syncthreads();
        // linear re-read + fully coalesced store: thread t -> row t>>1, half t&1
        // each half is 64 shorts = 8 x uint4
        {
            const int r = tid >> 1;
            const int c = tid & 1;
            if (e0 + r < N_EDGES) {
                const uint4* sp = (const uint4*)(sM + r * MROW + c * 64);
                uint4* dp = (uint4*)(msgs + (size_t)(e0 + r) * D + c * 64);
                uint4 v0 = sp[0], v1 = sp[1], v2 = sp[2], v3 = sp[3];
                uint4 v4 = sp[4], v5 = sp[5], v6 = sp[6], v7 = sp[7];
                dp[0] = v0; dp[1] = v1; dp[2] = v2; dp[3] = v3;
                dp[4] = v4; dp[5] = v5; dp[6] = v6; dp[7] = v7;
            }
        }
        // fused degree count
        if (tid < BE && e0 + tid < N_EDGES) atomicAdd(&cnt[sSrc[tid]], 1);
    } else {
#pragma unroll
        for (int nt = 0; nt < 2; nt++) {
            const int col = w * 32 + nt * 16 + (lane & 15);
            const float bF = bfp[col];
            const float bS = bsp[col];
#pragma unroll
            for (int mt = 0; mt < 8; mt++) {
#pragma unroll
                for (int r = 0; r < 4; r++) {
                    int mm = mt * 16 + ((lane >> 4) << 2) + r;
                    int eg = e0 + mm;
                    if (eg >= N_EDGES) continue;
                    float f = acc[mt][nt][r] + bF;
                    float s = acc[mt][nt + 2][r] + bS;
                    atomicAdd(agg + (size_t)sSrc[mm] * D + col,
                              fast_sigmoid(f) * fast_softplus(s));
                }
            }
        }
    }
}

// ---- CSR build: parallel scan (49 blocks x 1024), tiny top scan ----
__global__ __launch_bounds__(1024) void scan1_kernel(
    const int* __restrict__ cnt, int* __restrict__ ofs, int* __restrict__ bsum)
{
    __shared__ int sh[1024];
    const int t = threadIdx.x;
    const int n = blockIdx.x * 1024 + t;
    int c = (n < N_NODES) ? cnt[n] : 0;
    sh[t] = c;
    __syncthreads();
    for (int off = 1; off < 1024; off <<= 1) {
        int v = (t >= off) ? sh[t - off] : 0;
        __syncthreads();
        sh[t] += v;
        __syncthreads();
    }
    if (n < N_NODES) ofs[n] = sh[t] - c;      // block-local exclusive
    if (t == 1023) bsum[blockIdx.x] = sh[1023];
}

__global__ __launch_bounds__(64) void scan2_kernel(int* __restrict__ bsum)
{
    if (threadIdx.x == 0) {
        int v[49];
#pragma unroll
        for (int i = 0; i < 49; i++) v[i] = bsum[i];
        int run = 0;
#pragma unroll
        for (int i = 0; i < 49; i++) { bsum[i] = run; run += v[i]; }
    }
}

__global__ __launch_bounds__(512) void fill_kernel(
    const int* __restrict__ esrc, int* __restrict__ ofs,
    const int* __restrict__ bsum, int* __restrict__ eidx)
{
    int e = blockIdx.x * 512 + threadIdx.x;
    if (e < N_EDGES) {
        int s = esrc[e];
        int slot = atomicAdd(&ofs[s], 1) + bsum[s >> 10];
        eidx[slot] = e;
    }
}

// 2 nodes per block, 2 waves per node (even/odd edges), LDS combine.
__global__ __launch_bounds__(256) void gather_kernel(
    const unsigned short* __restrict__ msgs, const int* __restrict__ eidx,
    const int* __restrict__ cnt, const int* __restrict__ ofs,
    const int* __restrict__ bsum, float* __restrict__ agg)
{
    __shared__ float red[2][64][2];
    const int tid  = threadIdx.x;
    const int lane = tid & 63;
    const int w2   = (tid >> 6) & 1;
    const int h    = tid >> 7;
    const int n    = blockIdx.x * 2 + h;    // grid 25000, always < N_NODES
    const int deg  = cnt[n];
    const int base = bsum[n >> 10] + ofs[n] - deg;   // ofs advanced by fill
    float a0 = 0.0f, a1 = 0.0f;
    for (int j = w2; j < deg; j += 2) {
        int id = eidx[base + j];
        uint32_t p = *(const uint32_t*)(msgs + (size_t)id * D + 2 * lane);
        union { uint32_t u; float f; } c0, c1;
        c0.u = p << 16;
        c1.u = p & 0xFFFF0000u;
        a0 += c0.f; a1 += c1.f;
    }
    if (w2 == 1) { red[h][lane][0] = a0; red[h][lane][1] = a1; }
    __syncthreads();
    if (w2 == 0) {
        a0 += red[h][lane][0];
        a1 += red[h][lane][1];
        float2 o; o.x = a0; o.y = a1;
        *(float2*)(agg + (size_t)n * D + 2 * lane) = o;
    }
}

#define STATS_BLOCKS 128
__global__ __launch_bounds__(256) void bn_stats_kernel(
    const float* __restrict__ agg, float* __restrict__ stats)
{
    __shared__ float4 redS[256];
    __shared__ float4 redQ[256];
    const int c4 = threadIdx.x & 31;
    const int rg = threadIdx.x >> 5;
    const int rows = (N_NODES + STATS_BLOCKS - 1) / STATS_BLOCKS;
    const int r0 = blockIdx.x * rows;
    const int r1 = min(r0 + rows, N_NODES);
    const float4* a4 = (const float4*)agg;

    float4 s = {0, 0, 0, 0}, q = {0, 0, 0, 0};
    for (int r = r0 + rg; r < r1; r += 8) {
        float4 v = a4[(size_t)r * 32 + c4];
        s.x += v.x; s.y += v.y; s.z += v.z; s.w += v.w;
        q.x += v.x * v.x; q.y += v.y * v.y; q.z += v.z * v.z; q.w += v.w * v.w;
    }
    redS[threadIdx.x] = s;
    redQ[threadIdx.x] = q;
    __syncthreads();
    if (rg == 0) {
#pragma unroll
        for (int j = 1; j < 8; j++) {
            float4 ts = redS[c4 + j * 32], tq = redQ[c4 + j * 32];
            s.x += ts.x; s.y += ts.y; s.z += ts.z; s.w += ts.w;
            q.x += tq.x; q.y += tq.y; q.z += tq.z; q.w += tq.w;
        }
        atomicAdd(&stats[c4 * 4 + 0], s.x);
        atomicAdd(&stats[c4 * 4 + 1], s.y);
        atomicAdd(&stats[c4 * 4 + 2], s.z);
        atomicAdd(&stats[c4 * 4 + 3], s.w);
        atomicAdd(&stats[D + c4 * 4 + 0], q.x);
        atomicAdd(&stats[D + c4 * 4 + 1], q.y);
        atomicAdd(&stats[D + c4 * 4 + 2], q.z);
        atomicAdd(&stats[D + c4 * 4 + 3], q.w);
    }
}

__global__ __launch_bounds__(256) void bn_final_kernel(
    const float* __restrict__ x, const float* __restrict__ agg,
    const float* __restrict__ stats,
    const float* __restrict__ gamma, const float* __restrict__ beta,
    float* __restrict__ out)
{
    const int idx = blockIdx.x * blockDim.x + threadIdx.x;
    const int total4 = N_NODES * D / 4;
    if (idx >= total4) return;
    const int c4 = idx & (D / 4 - 1);
    const float inv_n = 1.0f / (float)N_NODES;

    float4 sm = *(const float4*)&stats[c4 * 4];
    float4 sq = *(const float4*)&stats[D + c4 * 4];
    float4 g  = *(const float4*)&gamma[c4 * 4];
    float4 b  = *(const float4*)&beta[c4 * 4];
    float4 xv = ((const float4*)x)[idx];
    float4 av = ((const float4*)agg)[idx];

    float4 o;
    {
        float mean = sm.x * inv_n, var = sq.x * inv_n - mean * mean;
        float is = rsqrtf(var + 1e-5f) * g.x;
        o.x = fast_softplus(xv.x + (av.x - mean) * is + b.x);
    }
    {
        float mean = sm.y * inv_n, var = sq.y * inv_n - mean * mean;
        float is = rsqrtf(var + 1e-5f) * g.y;
        o.y = fast_softplus(xv.y + (av.y - mean) * is + b.y);
    }
    {
        float mean = sm.z * inv_n, var = sq.z * inv_n - mean * mean;
        float is = rsqrtf(var + 1e-5f) * g.z;
        o.z = fast_softplus(xv.z + (av.z - mean) * is + b.z);
    }
    {
        float mean = sm.w * inv_n, var = sq.w * inv_n - mean * mean;
        float is = rsqrtf(var + 1e-5f) * g.w;
        o.w = fast_softplus(xv.w + (av.w - mean) * is + b.w);
    }
    ((float4*)out)[idx] = o;
}

extern "C" void kernel_launch(void* const* d_in, const int* in_sizes, int n_in,
                              void* d_out, int out_size, void* d_ws, size_t ws_size,
                              hipStream_t stream) {
    const float* x         = (const float*)d_in[0];
    const float* edge_attr = (const float*)d_in[1];
    const int*   esrc      = (const int*)d_in[2];
    const int*   etgt      = (const int*)d_in[3];
    const float* Wf        = (const float*)d_in[4];
    const float* bf_       = (const float*)d_in[5];
    const float* Ws        = (const float*)d_in[6];
    const float* bs_       = (const float*)d_in[7];
    const float* gamma     = (const float*)d_in[8];
    const float* beta      = (const float*)d_in[9];
    float* out = (float*)d_out;

    // ws layout (all sections 16B-aligned):
    float* agg   = (float*)d_ws;                           // 25,600,000 B
    float* stats = agg + (size_t)N_NODES * D;              //      1,024 B
    int*   cnt   = (int*)(stats + 2 * D);                  //    200,000 B
    int*   ofs   = cnt + N_NODES;                          //    200,000 B
    int*   bsum  = ofs + N_NODES;                          //      1,024 B (49 used)
    unsigned short* Wt = (unsigned short*)(bsum + 256);    //    221,184 B
    int*   eidx  = (int*)((char*)Wt + 221184);             //  2,000,000 B
    unsigned short* msgs = (unsigned short*)(eidx + N_EDGES); // 128,000,000 B
    const size_t NEED = 25600000ULL + 1024 + 200000 + 200000 + 1024
                      + 221184 + 2000000 + 128000000ULL;
    const int mode = (ws_size >= NEED) ? 1 : 0;

    wt_prepass<<<48, 256, 0, stream>>>(Wf, Ws, Wt);
    if (mode) {
        hipMemsetAsync(stats, 0, 1024 + 200000, stream);   // stats + cnt
        edge_msg_mfma<<<(N_EDGES + BE - 1) / BE, 256, 0, stream>>>(
            x, edge_attr, esrc, etgt, Wt, bf_, bs_, agg, msgs, cnt, 1);
        scan1_kernel<<<49, 1024, 0, stream>>>(cnt, ofs, bsum);
        scan2_kernel<<<1, 64, 0, stream>>>(bsum);
        fill_kernel<<<(N_EDGES + 511) / 512, 512, 0, stream>>>(esrc, ofs, bsum, eidx);
        gather_kernel<<<N_NODES / 2, 256, 0, stream>>>(msgs, eidx, cnt, ofs, bsum, agg);
    } else {
        hipMemsetAsync(d_ws, 0, ((size_t)N_NODES * D + 2 * D) * sizeof(float), stream);
        edge_msg_mfma<<<(N_EDGES + BE - 1) / BE, 256, 0, stream>>>(
            x, edge_attr, esrc, etgt, Wt, bf_, bs_, agg, msgs, cnt, 0);
    }
    bn_stats_kernel<<<STATS_BLOCKS, 256, 0, stream>>>(agg, stats);
    bn_final_kernel<<<(N_NODES * D / 4 + 255) / 256, 256, 0, stream>>>(
        x, agg, stats, gamma, beta, out);
}

// Round 3
// 649.244 us; speedup vs baseline: 1.0557x; 1.0557x over previous
//
#include <hip/hip_runtime.h>
#include <math.h>
#include <stdint.h>

#define N_NODES 50000
#define N_EDGES 500000
#define D 128
#define BE 128         // edges per block (512 threads, 8 waves: 2 edge-halves x 4 n-quarters)
#define NKT 6          // 384 / 64 K-tiles
#define WROW 72        // padded LDS/global row stride in bf16 (64 real + 8 pad)
#define MROW 136       // msg repack LDS row stride in bf16 (16B-aligned rows)
#define LOG2E 1.4426950408889634f
#define LN2   0.6931471805599453f

typedef __attribute__((ext_vector_type(8))) short bf16x8;
typedef __attribute__((ext_vector_type(4))) float floatx4;

__device__ __forceinline__ float fast_sigmoid(float v) {
    return __builtin_amdgcn_rcpf(1.0f + __builtin_amdgcn_exp2f(-v * LOG2E));
}
__device__ __forceinline__ float fast_softplus(float v) {
    float t = __builtin_amdgcn_exp2f(-fabsf(v) * LOG2E);
    return fmaxf(v, 0.0f) + __builtin_amdgcn_logf(1.0f + t) * LN2;
}
__device__ __forceinline__ uint32_t pack_bf16(float a, float b) {
    union { float f; uint32_t u; } ca, cb; ca.f = a; cb.f = b;
    return __builtin_amdgcn_perm(cb.u + 0x8000u, ca.u + 0x8000u, 0x07060302);
}
__device__ __forceinline__ unsigned short f2bf(float f) {
    union { float f; uint32_t u; } c; c.f = f;
    return (unsigned short)((c.u + 0x8000u) >> 16);
}

// Wt padded layout: [kt][n][72 bf16]; block (kt,i) converts k-chunk i for all n.
__global__ __launch_bounds__(256) void wt_prepass(
    const float* __restrict__ Wf, const float* __restrict__ Ws,
    unsigned short* __restrict__ Wt)
{
    const int kt = blockIdx.x >> 3;
    const int i  = blockIdx.x & 7;
    const int n  = threadIdx.x;
    const float* src = (n < 128) ? (Wf + n) : (Ws + (n - 128));
    const int k0 = kt * 64 + i * 8;
    uint32_t u[4];
#pragma unroll
    for (int j = 0; j < 4; j++) {
        float a = src[(size_t)(k0 + 2 * j) * D];
        float b = src[(size_t)(k0 + 2 * j + 1) * D];
        u[j] = pack_bf16(a, b);
    }
    uint4 v; v.x = u[0]; v.y = u[1]; v.z = u[2]; v.w = u[3];
    *(uint4*)(Wt + (size_t)(kt * 256 + n) * WROW + i * 8) = v;
}

// 128 edges x 256 outputs, K=384, bf16 MFMA 16x16x32, global_load_lds W staging.
// Proven round-0 inner structure, widened to 512 threads (2x4 wave grid):
// the 36.9KB W slab + 12 barriers now amortize over 128 edges instead of 64,
// and LDS/block=56.3KB -> 2 blocks/CU = 16 waves/CU (50% cap vs 37.5%).
// mode1: LDS-repacked coalesced bf16 msg stores + fused degree count.
// mode0: atomicAdd fallback.
__global__ __launch_bounds__(512, 4) void edge_msg_mfma(
    const float* __restrict__ x, const float* __restrict__ edge_attr,
    const int* __restrict__ esrc, const int* __restrict__ etgt,
    const unsigned short* __restrict__ Wt,
    const float* __restrict__ bfp, const float* __restrict__ bsp,
    float* __restrict__ agg, unsigned short* __restrict__ msgs,
    int* __restrict__ cnt, int mode)
{
    __shared__ unsigned short sW[256 * WROW];  // 36,864 B (reused as msg tile)
    __shared__ unsigned short sZ[BE * WROW];   // 18,432 B
    __shared__ int sSrc[BE];
    __shared__ int sTgt[BE];

    const int tid  = threadIdx.x;
    const int lane = tid & 63;
    const int w    = tid >> 6;      // 0..7
    const int wc   = w & 3;         // n-quarter (same role as round-0 'w')
    const int wr   = w >> 2;        // edge-half (0..1)
    const int e0   = blockIdx.x * BE;

    if (tid < BE) {
        sSrc[tid] = (e0 + tid < N_EDGES) ? esrc[e0 + tid] : 0;
    } else if (tid < 2 * BE) {
        int m = tid - BE;
        sTgt[m] = (e0 + m < N_EDGES) ? etgt[e0 + m] : 0;
    }
    __syncthreads();

    floatx4 acc[4][4];
#pragma unroll
    for (int mt = 0; mt < 4; mt++)
#pragma unroll
        for (int nt = 0; nt < 4; nt++) {
            floatx4 z = {0.f, 0.f, 0.f, 0.f};
            acc[mt][nt] = z;
        }

    const int zm = tid >> 2;          // 0..127
    const int zk = (tid & 3) * 16;

#pragma unroll 1
    for (int kt = 0; kt < NKT; kt++) {
        // ---- W slab DMA: 36 x 1024B chunks spread over 8 waves ----
        {
            const char* gbase = (const char*)Wt + (size_t)kt * 36864 + lane * 16;
            char* lbase = (char*)sW;
#pragma unroll
            for (int i = 0; i < 5; i++) {
                int c = w + i * 8;               // wave-uniform
                if (c < 36) {
                    __builtin_amdgcn_global_load_lds(
                        (const __attribute__((address_space(1))) void*)(gbase + c * 1024),
                        (__attribute__((address_space(3))) void*)(lbase + c * 1024),
                        16, 0, 0);
                }
            }
        }
        // ---- z-stage: 128 rows x 64 floats (this kt-half), 16 floats/thread ----
        {
            const float* zsrc;
            int half = (kt & 1) * 64;
            if (kt < 2)      zsrc = x + (size_t)sSrc[zm] * D + half;
            else if (kt < 4) zsrc = x + (size_t)sTgt[zm] * D + half;
            else {
                int eg = e0 + zm;
                zsrc = edge_attr + (size_t)(eg < N_EDGES ? eg : 0) * D + half;
            }
            float4 f0 = *(const float4*)(zsrc + zk);
            float4 f1 = *(const float4*)(zsrc + zk + 4);
            float4 f2 = *(const float4*)(zsrc + zk + 8);
            float4 f3 = *(const float4*)(zsrc + zk + 12);
            uint4 lo, hi;
            lo.x = pack_bf16(f0.x, f0.y); lo.y = pack_bf16(f0.z, f0.w);
            lo.z = pack_bf16(f1.x, f1.y); lo.w = pack_bf16(f1.z, f1.w);
            hi.x = pack_bf16(f2.x, f2.y); hi.y = pack_bf16(f2.z, f2.w);
            hi.z = pack_bf16(f3.x, f3.y); hi.w = pack_bf16(f3.z, f3.w);
            uint32_t* dz = (uint32_t*)(sZ + (size_t)zm * WROW) + (zk >> 1);
            *(uint4*)(dz)     = lo;
            *(uint4*)(dz + 4) = hi;
        }
        __syncthreads();

#pragma unroll
        for (int ks = 0; ks < 2; ks++) {
            const int kb = ks * 32 + (lane >> 4) * 8;
            bf16x8 afr[4];
#pragma unroll
            for (int mt = 0; mt < 4; mt++)
                afr[mt] = *(const bf16x8*)(sZ + (wr * 64 + mt * 16 + (lane & 15)) * WROW + kb);
            bf16x8 bfr[4];
#pragma unroll
            for (int nt = 0; nt < 4; nt++) {
                int n = (nt < 2) ? (wc * 32 + nt * 16 + (lane & 15))
                                 : (128 + wc * 32 + (nt - 2) * 16 + (lane & 15));
                bfr[nt] = *(const bf16x8*)(sW + n * WROW + kb);
            }
#pragma unroll
            for (int mt = 0; mt < 4; mt++)
#pragma unroll
                for (int nt = 0; nt < 4; nt++)
                    acc[mt][nt] = __builtin_amdgcn_mfma_f32_16x16x32_bf16(
                        afr[mt], bfr[nt], acc[mt][nt], 0, 0, 0);
        }
        __syncthreads();
    }

    // ---- epilogue: bias + gate ----
    if (mode) {
        unsigned short* sM = sW;   // reuse: 128 x MROW bf16 tile (34,816 B)
#pragma unroll
        for (int nt = 0; nt < 2; nt++) {
            const int col = wc * 32 + nt * 16 + (lane & 15);
            const float bF = bfp[col];
            const float bS = bsp[col];
#pragma unroll
            for (int mt = 0; mt < 4; mt++) {
#pragma unroll
                for (int r = 0; r < 4; r++) {
                    int mm = wr * 64 + mt * 16 + (lane >> 4) * 4 + r;
                    float f = acc[mt][nt][r] + bF;
                    float s = acc[mt][nt + 2][r] + bS;
                    sM[mm * MROW + col] = f2bf(fast_sigmoid(f) * fast_softplus(s));
                }
            }
        }
        __syncthreads();
        // linear re-read + fully coalesced store: thread t -> row t>>2, chunk t&3
        {
            const int r = tid >> 2;
            const int c = tid & 3;
            if (e0 + r < N_EDGES) {
                const uint4* sp = (const uint4*)(sM + r * MROW + c * 32);
                uint4 v0 = sp[0], v1 = sp[1], v2 = sp[2], v3 = sp[3];
                uint4* dp = (uint4*)(msgs + (size_t)(e0 + r) * D + c * 32);
                dp[0] = v0; dp[1] = v1; dp[2] = v2; dp[3] = v3;
            }
        }
        // fused degree count
        if (tid < BE && e0 + tid < N_EDGES) atomicAdd(&cnt[sSrc[tid]], 1);
    } else {
#pragma unroll
        for (int nt = 0; nt < 2; nt++) {
            const int col = wc * 32 + nt * 16 + (lane & 15);
            const float bF = bfp[col];
            const float bS = bsp[col];
#pragma unroll
            for (int mt = 0; mt < 4; mt++) {
#pragma unroll
                for (int r = 0; r < 4; r++) {
                    int mm = wr * 64 + mt * 16 + (lane >> 4) * 4 + r;
                    int eg = e0 + mm;
                    if (eg >= N_EDGES) continue;
                    float f = acc[mt][nt][r] + bF;
                    float s = acc[mt][nt + 2][r] + bS;
                    atomicAdd(agg + (size_t)sSrc[mm] * D + col,
                              fast_sigmoid(f) * fast_softplus(s));
                }
            }
        }
    }
}

// ---- CSR build: parallel scan (49 blocks x 1024), tiny top scan ----
__global__ __launch_bounds__(1024) void scan1_kernel(
    const int* __restrict__ cnt, int* __restrict__ ofs, int* __restrict__ bsum)
{
    __shared__ int sh[1024];
    const int t = threadIdx.x;
    const int n = blockIdx.x * 1024 + t;
    int c = (n < N_NODES) ? cnt[n] : 0;
    sh[t] = c;
    __syncthreads();
    for (int off = 1; off < 1024; off <<= 1) {
        int v = (t >= off) ? sh[t - off] : 0;
        __syncthreads();
        sh[t] += v;
        __syncthreads();
    }
    if (n < N_NODES) ofs[n] = sh[t] - c;      // block-local exclusive
    if (t == 1023) bsum[blockIdx.x] = sh[1023];
}

__global__ __launch_bounds__(64) void scan2_kernel(int* __restrict__ bsum)
{
    if (threadIdx.x == 0) {
        int v[49];
#pragma unroll
        for (int i = 0; i < 49; i++) v[i] = bsum[i];
        int run = 0;
#pragma unroll
        for (int i = 0; i < 49; i++) { bsum[i] = run; run += v[i]; }
    }
}

__global__ __launch_bounds__(512) void fill_kernel(
    const int* __restrict__ esrc, int* __restrict__ ofs,
    const int* __restrict__ bsum, int* __restrict__ eidx)
{
    int e = blockIdx.x * 512 + threadIdx.x;
    if (e < N_EDGES) {
        int s = esrc[e];
        int slot = atomicAdd(&ofs[s], 1) + bsum[s >> 10];
        eidx[slot] = e;
    }
}

// 2 nodes per block, 2 waves per node (even/odd edges), LDS combine.
__global__ __launch_bounds__(256) void gather_kernel(
    const unsigned short* __restrict__ msgs, const int* __restrict__ eidx,
    const int* __restrict__ cnt, const int* __restrict__ ofs,
    const int* __restrict__ bsum, float* __restrict__ agg)
{
    __shared__ float red[2][64][2];
    const int tid  = threadIdx.x;
    const int lane = tid & 63;
    const int w2   = (tid >> 6) & 1;
    const int h    = tid >> 7;
    const int n    = blockIdx.x * 2 + h;    // grid 25000, always < N_NODES
    const int deg  = cnt[n];
    const int base = bsum[n >> 10] + ofs[n] - deg;   // ofs advanced by fill
    float a0 = 0.0f, a1 = 0.0f;
    for (int j = w2; j < deg; j += 2) {
        int id = eidx[base + j];
        uint32_t p = *(const uint32_t*)(msgs + (size_t)id * D + 2 * lane);
        union { uint32_t u; float f; } c0, c1;
        c0.u = p << 16;
        c1.u = p & 0xFFFF0000u;
        a0 += c0.f; a1 += c1.f;
    }
    if (w2 == 1) { red[h][lane][0] = a0; red[h][lane][1] = a1; }
    __syncthreads();
    if (w2 == 0) {
        a0 += red[h][lane][0];
        a1 += red[h][lane][1];
        float2 o; o.x = a0; o.y = a1;
        *(float2*)(agg + (size_t)n * D + 2 * lane) = o;
    }
}

#define STATS_BLOCKS 128
__global__ __launch_bounds__(256) void bn_stats_kernel(
    const float* __restrict__ agg, float* __restrict__ stats)
{
    __shared__ float4 redS[256];
    __shared__ float4 redQ[256];
    const int c4 = threadIdx.x & 31;
    const int rg = threadIdx.x >> 5;
    const int rows = (N_NODES + STATS_BLOCKS - 1) / STATS_BLOCKS;
    const int r0 = blockIdx.x * rows;
    const int r1 = min(r0 + rows, N_NODES);
    const float4* a4 = (const float4*)agg;

    float4 s = {0, 0, 0, 0}, q = {0, 0, 0, 0};
    for (int r = r0 + rg; r < r1; r += 8) {
        float4 v = a4[(size_t)r * 32 + c4];
        s.x += v.x; s.y += v.y; s.z += v.z; s.w += v.w;
        q.x += v.x * v.x; q.y += v.y * v.y; q.z += v.z * v.z; q.w += v.w * v.w;
    }
    redS[threadIdx.x] = s;
    redQ[threadIdx.x] = q;
    __syncthreads();
    if (rg == 0) {
#pragma unroll
        for (int j = 1; j < 8; j++) {
            float4 ts = redS[c4 + j * 32], tq = redQ[c4 + j * 32];
            s.x += ts.x; s.y += ts.y; s.z += ts.z; s.w += ts.w;
            q.x += tq.x; q.y += tq.y; q.z += tq.z; q.w += tq.w;
        }
        atomicAdd(&stats[c4 * 4 + 0], s.x);
        atomicAdd(&stats[c4 * 4 + 1], s.y);
        atomicAdd(&stats[c4 * 4 + 2], s.z);
        atomicAdd(&stats[c4 * 4 + 3], s.w);
        atomicAdd(&stats[D + c4 * 4 + 0], q.x);
        atomicAdd(&stats[D + c4 * 4 + 1], q.y);
        atomicAdd(&stats[D + c4 * 4 + 2], q.z);
        atomicAdd(&stats[D + c4 * 4 + 3], q.w);
    }
}

__global__ __launch_bounds__(256) void bn_final_kernel(
    const float* __restrict__ x, const float* __restrict__ agg,
    const float* __restrict__ stats,
    const float* __restrict__ gamma, const float* __restrict__ beta,
    float* __restrict__ out)
{
    const int idx = blockIdx.x * blockDim.x + threadIdx.x;
    const int total4 = N_NODES * D / 4;
    if (idx >= total4) return;
    const int c4 = idx & (D / 4 - 1);
    const float inv_n = 1.0f / (float)N_NODES;

    float4 sm = *(const float4*)&stats[c4 * 4];
    float4 sq = *(const float4*)&stats[D + c4 * 4];
    float4 g  = *(const float4*)&gamma[c4 * 4];
    float4 b  = *(const float4*)&beta[c4 * 4];
    float4 xv = ((const float4*)x)[idx];
    float4 av = ((const float4*)agg)[idx];

    float4 o;
    {
        float mean = sm.x * inv_n, var = sq.x * inv_n - mean * mean;
        float is = rsqrtf(var + 1e-5f) * g.x;
        o.x = fast_softplus(xv.x + (av.x - mean) * is + b.x);
    }
    {
        float mean = sm.y * inv_n, var = sq.y * inv_n - mean * mean;
        float is = rsqrtf(var + 1e-5f) * g.y;
        o.y = fast_softplus(xv.y + (av.y - mean) * is + b.y);
    }
    {
        float mean = sm.z * inv_n, var = sq.z * inv_n - mean * mean;
        float is = rsqrtf(var + 1e-5f) * g.z;
        o.z = fast_softplus(xv.z + (av.z - mean) * is + b.z);
    }
    {
        float mean = sm.w * inv_n, var = sq.w * inv_n - mean * mean;
        float is = rsqrtf(var + 1e-5f) * g.w;
        o.w = fast_softplus(xv.w + (av.w - mean) * is + b.w);
    }
    ((float4*)out)[idx] = o;
}

extern "C" void kernel_launch(void* const* d_in, const int* in_sizes, int n_in,
                              void* d_out, int out_size, void* d_ws, size_t ws_size,
                              hipStream_t stream) {
    const float* x         = (const float*)d_in[0];
    const float* edge_attr = (const float*)d_in[1];
    const int*   esrc      = (const int*)d_in[2];
    const int*   etgt      = (const int*)d_in[3];
    const float* Wf        = (const float*)d_in[4];
    const float* bf_       = (const float*)d_in[5];
    const float* Ws        = (const float*)d_in[6];
    const float* bs_       = (const float*)d_in[7];
    const float* gamma     = (const float*)d_in[8];
    const float* beta      = (const float*)d_in[9];
    float* out = (float*)d_out;

    // ws layout (all sections 16B-aligned):
    float* agg   = (float*)d_ws;                           // 25,600,000 B
    float* stats = agg + (size_t)N_NODES * D;              //      1,024 B
    int*   cnt   = (int*)(stats + 2 * D);                  //    200,000 B
    int*   ofs   = cnt + N_NODES;                          //    200,000 B
    int*   bsum  = ofs + N_NODES;                          //      1,024 B (49 used)
    unsigned short* Wt = (unsigned short*)(bsum + 256);    //    221,184 B
    int*   eidx  = (int*)((char*)Wt + 221184);             //  2,000,000 B
    unsigned short* msgs = (unsigned short*)(eidx + N_EDGES); // 128,000,000 B
    const size_t NEED = 25600000ULL + 1024 + 200000 + 200000 + 1024
                      + 221184 + 2000000 + 128000000ULL;
    const int mode = (ws_size >= NEED) ? 1 : 0;

    wt_prepass<<<48, 256, 0, stream>>>(Wf, Ws, Wt);
    if (mode) {
        hipMemsetAsync(stats, 0, 1024 + 200000, stream);   // stats + cnt
        edge_msg_mfma<<<(N_EDGES + BE - 1) / BE, 512, 0, stream>>>(
            x, edge_attr, esrc, etgt, Wt, bf_, bs_, agg, msgs, cnt, 1);
        scan1_kernel<<<49, 1024, 0, stream>>>(cnt, ofs, bsum);
        scan2_kernel<<<1, 64, 0, stream>>>(bsum);
        fill_kernel<<<(N_EDGES + 511) / 512, 512, 0, stream>>>(esrc, ofs, bsum, eidx);
        gather_kernel<<<N_NODES / 2, 256, 0, stream>>>(msgs, eidx, cnt, ofs, bsum, agg);
    } else {
        hipMemsetAsync(d_ws, 0, ((size_t)N_NODES * D + 2 * D) * sizeof(float), stream);
        edge_msg_mfma<<<(N_EDGES + BE - 1) / BE, 512, 0, stream>>>(
            x, edge_attr, esrc, etgt, Wt, bf_, bs_, agg, msgs, cnt, 0);
    }
    bn_stats_kernel<<<STATS_BLOCKS, 256, 0, stream>>>(agg, stats);
    bn_final_kernel<<<(N_NODES * D / 4 + 255) / 256, 256, 0, stream>>>(
        x, agg, stats, gamma, beta, out);
}